// Round 1
// baseline (419.852 us; speedup 1.0000x reference)
//
#include <hip/hip_runtime.h>
#include <hip/hip_bf16.h>
#include <math.h>

#define Bb 8
#define Tt 512
#define Cc 512
#define Hh 8
#define HKV 4
#define Dd 64

__device__ __forceinline__ float wave_reduce_max(float v) {
#pragma unroll
  for (int off = 32; off > 0; off >>= 1) v = fmaxf(v, __shfl_xor(v, off, 64));
  return v;
}
__device__ __forceinline__ float wave_reduce_sum(float v) {
#pragma unroll
  for (int off = 32; off > 0; off >>= 1) v += __shfl_xor(v, off, 64);
  return v;
}

// ---------------- QKV GEMM: x(4096x512) @ [Wq|Wk|Wv] -> q,k,v ----------------
__global__ __launch_bounds__(256) void qkv_gemm(
    const float* __restrict__ x, const float* __restrict__ Wq,
    const float* __restrict__ Wk, const float* __restrict__ Wv,
    float* __restrict__ q, float* __restrict__ k, float* __restrict__ v) {
  __shared__ float As[64][20];
  __shared__ float Bs[16][68];
  const int m0 = blockIdx.x * 64;
  const int n0 = blockIdx.y * 64;
  const float* Wsrc;
  int ldw, noff;
  if (n0 < 512)      { Wsrc = Wq; ldw = 512; noff = n0; }
  else if (n0 < 768) { Wsrc = Wk; ldw = 256; noff = n0 - 512; }
  else               { Wsrc = Wv; ldw = 256; noff = n0 - 768; }
  const int t = threadIdx.x;
  const int tx = t & 15, ty = t >> 4;
  const int am = t >> 2, ak = (t & 3) << 2;
  const int bk = t >> 4, bn = (t & 15) << 2;
  float acc[4][4] = {};
  for (int k0 = 0; k0 < Cc; k0 += 16) {
    float4 a4 = *(const float4*)&x[(m0 + am) * Cc + k0 + ak];
    float4 b4 = *(const float4*)&Wsrc[(k0 + bk) * ldw + noff + bn];
    *(float4*)&As[am][ak] = a4;
    *(float4*)&Bs[bk][bn] = b4;
    __syncthreads();
#pragma unroll
    for (int kk = 0; kk < 16; ++kk) {
      float4 b = *(float4*)&Bs[kk][tx << 2];
#pragma unroll
      for (int i = 0; i < 4; ++i) {
        float a = As[(ty << 2) + i][kk];
        acc[i][0] = fmaf(a, b.x, acc[i][0]);
        acc[i][1] = fmaf(a, b.y, acc[i][1]);
        acc[i][2] = fmaf(a, b.z, acc[i][2]);
        acc[i][3] = fmaf(a, b.w, acc[i][3]);
      }
    }
    __syncthreads();
  }
#pragma unroll
  for (int i = 0; i < 4; ++i) {
    int m = m0 + (ty << 2) + i;
    float4 val = make_float4(acc[i][0], acc[i][1], acc[i][2], acc[i][3]);
    if (n0 < 512)      *(float4*)&q[m * 512 + n0 + (tx << 2)] = val;
    else if (n0 < 768) *(float4*)&k[m * 256 + (n0 - 512) + (tx << 2)] = val;
    else               *(float4*)&v[m * 256 + (n0 - 768) + (tx << 2)] = val;
  }
}

// ---------------- Proj GEMM: y(4096x512) @ Wproj(512x512) -> out ----------------
__global__ __launch_bounds__(256) void proj_gemm(
    const float* __restrict__ A, const float* __restrict__ W,
    float* __restrict__ out) {
  __shared__ float As[64][20];
  __shared__ float Bs[16][68];
  const int m0 = blockIdx.x * 64;
  const int n0 = blockIdx.y * 64;
  const int t = threadIdx.x;
  const int tx = t & 15, ty = t >> 4;
  const int am = t >> 2, ak = (t & 3) << 2;
  const int bk = t >> 4, bn = (t & 15) << 2;
  float acc[4][4] = {};
  for (int k0 = 0; k0 < Cc; k0 += 16) {
    float4 a4 = *(const float4*)&A[(m0 + am) * Cc + k0 + ak];
    float4 b4 = *(const float4*)&W[(k0 + bk) * 512 + n0 + bn];
    *(float4*)&As[am][ak] = a4;
    *(float4*)&Bs[bk][bn] = b4;
    __syncthreads();
#pragma unroll
    for (int kk = 0; kk < 16; ++kk) {
      float4 b = *(float4*)&Bs[kk][tx << 2];
#pragma unroll
      for (int i = 0; i < 4; ++i) {
        float a = As[(ty << 2) + i][kk];
        acc[i][0] = fmaf(a, b.x, acc[i][0]);
        acc[i][1] = fmaf(a, b.y, acc[i][1]);
        acc[i][2] = fmaf(a, b.z, acc[i][2]);
        acc[i][3] = fmaf(a, b.w, acc[i][3]);
      }
    }
    __syncthreads();
  }
#pragma unroll
  for (int i = 0; i < 4; ++i) {
    int m = m0 + (ty << 2) + i;
    *(float4*)&out[m * 512 + n0 + (tx << 2)] =
        make_float4(acc[i][0], acc[i][1], acc[i][2], acc[i][3]);
  }
}

// ---------------- RMS-norm of q and k rows (64-wide) ----------------
__global__ __launch_bounds__(256) void norm_qk(float* __restrict__ q,
                                               float* __restrict__ k) {
  int w = blockIdx.x * 4 + (threadIdx.x >> 6);
  int lane = threadIdx.x & 63;
  float* row = (w < Bb * Tt * Hh) ? (q + w * 64) : (k + (w - Bb * Tt * Hh) * 64);
  float val = row[lane];
  float ss = wave_reduce_sum(val * val);
  row[lane] = val * 8.0f * rsqrtf(ss + 1e-6f);
}

// ---------------- Pw[h][delta+511][d] table ----------------
__global__ __launch_bounds__(256) void build_pw(const float* __restrict__ P,
                                                const float* __restrict__ sigma,
                                                float* __restrict__ Pw) {
  int idx = blockIdx.x * blockDim.x + threadIdx.x;
  if (idx >= Hh * 1023 * 64) return;
  int d = idx & 63;
  int rem = idx >> 6;
  int dd = rem % 1023;
  int h = rem / 1023;
  float s = fabsf(sigma[h]) + 1e-6f;
  float delta = (float)(dd - 511);
  float dt = 128.0f * tanhf(delta / s) + 128.0f;
  float lo = floorf(dt);
  int ilo = (int)lo;
  float frac = dt - lo;
  ilo = max(0, min(ilo, 256));
  int ihi = min(ilo + 1, 256);
  const float* Pb = P + h * 257 * 64;
  Pw[idx] = (1.0f - frac) * Pb[ilo * 64 + d] + frac * Pb[ihi * 64 + d];
}

// ---------------- Attention: flash-style with positional Hadamard weight ----------------
// grid (T/16, B*H), block 256 (4 waves x 4 rows each)
__global__ __launch_bounds__(256) void attn(
    const float* __restrict__ q, const float* __restrict__ k,
    const float* __restrict__ v, const float* __restrict__ Pw,
    float* __restrict__ y) {
  __shared__ float Ks[64][68];
  __shared__ float Vs[64][68];
  __shared__ float PwS[80][68];
  __shared__ float qS[16][68];
  __shared__ float pS[4][64][4];

  const int t = threadIdx.x;
  const int w = t >> 6;
  const int lane = t & 63;
  const int bh = blockIdx.y;
  const int b = bh >> 3;
  const int h = bh & 7;
  const int hkv = h >> 1;
  const int i0 = blockIdx.x * 16;

  {
    int row = t >> 4, dc = (t & 15) << 2;
    *(float4*)&qS[row][dc] =
        *(const float4*)&q[((b * Tt + i0 + row) * Hh + h) * Dd + dc];
  }

  float m_run[4], l_run[4], o_run[4];
#pragma unroll
  for (int r = 0; r < 4; ++r) { m_run[r] = -1e30f; l_run[r] = 0.0f; o_run[r] = 0.0f; }

  const int i_base = i0 + (w << 2);
  const int i_max_blk = i0 + 15;

  for (int jt0 = 0; jt0 <= i_max_blk; jt0 += 64) {
    __syncthreads();
    {
      int jr = t >> 2, dc = (t & 3) << 4;
      const float* kp = &k[((b * Tt + jt0 + jr) * HKV + hkv) * Dd + dc];
      const float* vp = &v[((b * Tt + jt0 + jr) * HKV + hkv) * Dd + dc];
#pragma unroll
      for (int c = 0; c < 4; ++c) {
        *(float4*)&Ks[jr][dc + c * 4] = *(const float4*)&kp[c * 4];
        *(float4*)&Vs[jr][dc + c * 4] = *(const float4*)&vp[c * 4];
      }
      const int ddbase = i0 - jt0 + 448;  // dd for PwS row 0
      const float* pwp = &Pw[(h * 1023 + (jr + ddbase)) * 64 + dc];
#pragma unroll
      for (int c = 0; c < 4; ++c)
        *(float4*)&PwS[jr][dc + c * 4] = *(const float4*)&pwp[c * 4];
      int pr2 = jr + 64;
      if (pr2 < 79) {
        const float* pwp2 = &Pw[(h * 1023 + (pr2 + ddbase)) * 64 + dc];
#pragma unroll
        for (int c = 0; c < 4; ++c)
          *(float4*)&PwS[pr2][dc + c * 4] = *(const float4*)&pwp2[c * 4];
      }
    }
    __syncthreads();

    // score phase: lane = j
    float s[4] = {0.0f, 0.0f, 0.0f, 0.0f};
#pragma unroll 4
    for (int dc = 0; dc < 64; dc += 4) {
      float4 kk4 = *(float4*)&Ks[lane][dc];
#pragma unroll
      for (int r = 0; r < 4; ++r) {
        float4 q4 = *(float4*)&qS[(w << 2) + r][dc];
        float4 p4 = *(float4*)&PwS[(w << 2) + r + 63 - lane][dc];
        s[r] = fmaf(q4.x * p4.x, kk4.x, s[r]);
        s[r] = fmaf(q4.y * p4.y, kk4.y, s[r]);
        s[r] = fmaf(q4.z * p4.z, kk4.z, s[r]);
        s[r] = fmaf(q4.w * p4.w, kk4.w, s[r]);
      }
    }
    int j = jt0 + lane;
#pragma unroll
    for (int r = 0; r < 4; ++r) {
      int i_r = i_base + r;
      float p = 0.0f;
      if (jt0 <= i_r) {
        float sv = (j <= i_r) ? s[r] * 0.125f : -1e30f;
        float mnew = fmaxf(m_run[r], wave_reduce_max(sv));
        p = __expf(sv - mnew);
        float alpha = __expf(m_run[r] - mnew);
        l_run[r] = l_run[r] * alpha + wave_reduce_sum(p);
        o_run[r] *= alpha;
        m_run[r] = mnew;
      }
      pS[w][lane][r] = p;
    }
    // PV phase: lane = d (same-wave LDS ordering guarantees pS visibility)
#pragma unroll 8
    for (int jj = 0; jj < 64; ++jj) {
      float4 p4 = *(float4*)&pS[w][jj][0];
      float vv = Vs[jj][lane];
      o_run[0] = fmaf(p4.x, vv, o_run[0]);
      o_run[1] = fmaf(p4.y, vv, o_run[1]);
      o_run[2] = fmaf(p4.z, vv, o_run[2]);
      o_run[3] = fmaf(p4.w, vv, o_run[3]);
    }
  }
#pragma unroll
  for (int r = 0; r < 4; ++r) {
    int i_r = i_base + r;
    y[((b * Tt + i_r) * Hh + h) * Dd + lane] = o_run[r] / l_run[r];
  }
}

extern "C" void kernel_launch(void* const* d_in, const int* in_sizes, int n_in,
                              void* d_out, int out_size, void* d_ws, size_t ws_size,
                              hipStream_t stream) {
  const float* x     = (const float*)d_in[0];
  const float* Wq    = (const float*)d_in[1];
  const float* Wk    = (const float*)d_in[2];
  const float* Wv    = (const float*)d_in[3];
  const float* Wproj = (const float*)d_in[4];
  const float* P     = (const float*)d_in[5];
  const float* sigma = (const float*)d_in[6];
  float* out = (float*)d_out;

  float* ws = (float*)d_ws;
  float* q  = ws;                     // 2097152
  float* k  = q + 2097152;            // 1048576
  float* v  = k + 1048576;            // 1048576
  float* Pw = v + 1048576;            // 523776
  float* y  = Pw + 523776;            // 2097152

  qkv_gemm<<<dim3(64, 16), 256, 0, stream>>>(x, Wq, Wk, Wv, q, k, v);
  norm_qk<<<dim3(12288), 256, 0, stream>>>(q, k);
  build_pw<<<dim3(2046), 256, 0, stream>>>(P, sigma, Pw);
  attn<<<dim3(32, 64), 256, 0, stream>>>(q, k, v, Pw, y);
  proj_gemm<<<dim3(64, 8), 256, 0, stream>>>(y, Wproj, out);
}